// Round 1
// baseline (6350.505 us; speedup 1.0000x reference)
//
#include <hip/hip_runtime.h>

#define N_NODES_C 100000
#define N_EDGES_C 3200000
#define DIM_C 128
#define LN_EPS_C 1e-5f

// deg[i] = 1.0 (self loop)
__global__ void init_deg_kernel(float* __restrict__ deg) {
    int i = blockIdx.x * blockDim.x + threadIdx.x;
    if (i < N_NODES_C) deg[i] = 1.0f;
}

// deg[col[e]] += 1 for every real edge
__global__ void count_deg_kernel(const int* __restrict__ col, float* __restrict__ deg) {
    int e = blockIdx.x * blockDim.x + threadIdx.x;
    if (e < N_EDGES_C) atomicAdd(&deg[col[e]], 1.0f);
}

// deg -> deg^{-1/2} in place (deg >= 1 always)
__global__ void rsqrt_deg_kernel(float* __restrict__ deg) {
    int i = blockIdx.x * blockDim.x + threadIdx.x;
    if (i < N_NODES_C) deg[i] = rsqrtf(deg[i]);
}

// 32 threads per edge; each lane does a float4 of x[row] and 4 scalar atomics into agg[col]
__global__ void scatter_kernel(const float* __restrict__ x,
                               const int* __restrict__ row,
                               const int* __restrict__ col,
                               const float* __restrict__ dis,
                               float* __restrict__ agg) {
    long long t = (long long)blockIdx.x * blockDim.x + threadIdx.x;
    int e = (int)(t >> 5);
    if (e >= N_EDGES_C) return;
    int lane = (int)(t & 31);
    int r = row[e];
    int c = col[e];
    float norm = dis[r] * dis[c];
    float4 xv = ((const float4*)(x + (size_t)r * DIM_C))[lane];
    float* dst = agg + (size_t)c * DIM_C + (size_t)lane * 4;
    atomicAdd(dst + 0, norm * xv.x);
    atomicAdd(dst + 1, norm * xv.y);
    atomicAdd(dst + 2, norm * xv.z);
    atomicAdd(dst + 3, norm * xv.w);
}

// One 128-thread block per node. In-place on out (== agg buffer):
// a = agg_row + (1/deg)*x_row ; y = a @ W^T + b ; LayerNorm(y)
__global__ void __launch_bounds__(128) linear_ln_kernel(
        const float* __restrict__ x,
        const float* __restrict__ dis,
        const float* __restrict__ W,
        const float* __restrict__ bias,
        const float* __restrict__ gamma,
        const float* __restrict__ beta,
        float* __restrict__ out) {
    int i = blockIdx.x;
    int d = threadIdx.x;  // 0..127

    __shared__ float a[DIM_C];
    __shared__ float red[4];

    float dis_i = dis[i];
    float self_norm = dis_i * dis_i;  // = 1/deg[i]
    size_t base = (size_t)i * DIM_C;
    a[d] = out[base + d] + self_norm * x[base + d];
    __syncthreads();

    float acc = bias[d];
    const float* w = W + (size_t)d * DIM_C;
#pragma unroll
    for (int k = 0; k < DIM_C; k += 4) {
        float4 av = *(const float4*)(a + k);   // LDS broadcast
        float4 wv = *(const float4*)(w + k);   // L1/L2 cached
        acc += av.x * wv.x + av.y * wv.y + av.z * wv.z + av.w * wv.w;
    }

    // Block reduction over 128 values (2 waves) for mean / E[x^2]
    float s = acc, s2 = acc * acc;
#pragma unroll
    for (int off = 32; off > 0; off >>= 1) {
        s  += __shfl_down(s,  off, 64);
        s2 += __shfl_down(s2, off, 64);
    }
    int lane = d & 63, wid = d >> 6;
    if (lane == 0) { red[wid] = s; red[2 + wid] = s2; }
    __syncthreads();
    float S  = red[0] + red[1];
    float S2 = red[2] + red[3];
    float mean = S * (1.0f / DIM_C);
    float var  = S2 * (1.0f / DIM_C) - mean * mean;
    float inv  = rsqrtf(var + LN_EPS_C);

    out[base + d] = (acc - mean) * inv * gamma[d] + beta[d];
}

extern "C" void kernel_launch(void* const* d_in, const int* in_sizes, int n_in,
                              void* d_out, int out_size, void* d_ws, size_t ws_size,
                              hipStream_t stream) {
    const float* x     = (const float*)d_in[0];
    const int*   row   = (const int*)d_in[1];              // edge_index[0]
    const int*   col   = ((const int*)d_in[1]) + N_EDGES_C; // edge_index[1]
    const float* W     = (const float*)d_in[2];
    const float* bias  = (const float*)d_in[3];
    const float* gamma = (const float*)d_in[4];
    const float* beta  = (const float*)d_in[5];
    float* out = (float*)d_out;

    float* deg = (float*)d_ws;  // N_NODES floats; becomes deg^{-1/2}

    // Zero the aggregation buffer (d_out is poisoned before every timed call)
    hipMemsetAsync(d_out, 0, (size_t)N_NODES_C * DIM_C * sizeof(float), stream);

    init_deg_kernel<<<(N_NODES_C + 255) / 256, 256, 0, stream>>>(deg);
    count_deg_kernel<<<(N_EDGES_C + 255) / 256, 256, 0, stream>>>(col, deg);
    rsqrt_deg_kernel<<<(N_NODES_C + 255) / 256, 256, 0, stream>>>(deg);

    // 32 threads per edge
    long long scatter_threads = (long long)N_EDGES_C * 32;
    int scatter_blocks = (int)((scatter_threads + 255) / 256);
    scatter_kernel<<<scatter_blocks, 256, 0, stream>>>(x, row, col, deg, out);

    linear_ln_kernel<<<N_NODES_C, 128, 0, stream>>>(x, deg, W, bias, gamma, beta, out);
}

// Round 2
// 1468.207 us; speedup vs baseline: 4.3253x; 4.3253x over previous
//
#include <hip/hip_runtime.h>

#define N_NODES 100000
#define N_EDGES 3200000
#define DIM 128
#define LN_EPS 1e-5f
#define NBLK 391            // ceil(N_NODES / 256)

// ---- workspace layout (4-byte elements) ----
// cnt    : int  [N_NODES]      @ 0
// off    : int  [N_NODES+1]    @ 100000
// cursor : int  [N_NODES]      @ 200004
// dis    : float[N_NODES]      @ 300004
// csr    : int  [N_EDGES]      @ 400004
// bsum   : int  [512]          @ 3600004
// bexc   : int  [512]          @ 3600516
#define WS_CNT    0
#define WS_OFF    100000
#define WS_CURSOR 200004
#define WS_DIS    300004
#define WS_CSR    400004
#define WS_BSUM   3600004
#define WS_BEXC   3600516

// ---- degree count: cnt[col[e]] += 1 ----
__global__ void k_count(const int* __restrict__ col, int* __restrict__ cnt) {
    int e = blockIdx.x * blockDim.x + threadIdx.x;
    if (e < N_EDGES) atomicAdd(&cnt[col[e]], 1);
}

// ---- per-256-chunk sums of cnt ----
__global__ void k_blockreduce(const int* __restrict__ cnt, int* __restrict__ bsum) {
    __shared__ int s[256];
    int i = blockIdx.x * 256 + threadIdx.x;
    s[threadIdx.x] = (i < N_NODES) ? cnt[i] : 0;
    __syncthreads();
    for (int st = 128; st > 0; st >>= 1) {
        if (threadIdx.x < st) s[threadIdx.x] += s[threadIdx.x + st];
        __syncthreads();
    }
    if (threadIdx.x == 0) bsum[blockIdx.x] = s[0];
}

// ---- scan the 391 chunk sums (one block) ----
__global__ void k_scanbsums(const int* __restrict__ bsum, int* __restrict__ bexc,
                            int* __restrict__ off) {
    __shared__ int s[512];
    int t = threadIdx.x;
    int v0 = (t < NBLK) ? bsum[t] : 0;
    s[t] = v0;
    __syncthreads();
    for (int st = 1; st < 512; st <<= 1) {
        int v = (t >= st) ? s[t - st] : 0;
        __syncthreads();
        s[t] += v;
        __syncthreads();
    }
    if (t < NBLK) bexc[t] = s[t] - v0;   // exclusive
    if (t == 0) off[N_NODES] = N_EDGES;
}

// ---- per-chunk exclusive scan + chunk base -> off, cursor ----
__global__ void k_blockscan(const int* __restrict__ cnt, const int* __restrict__ bexc,
                            int* __restrict__ off, int* __restrict__ cursor) {
    __shared__ int s[256];
    int i = blockIdx.x * 256 + threadIdx.x;
    int v = (i < N_NODES) ? cnt[i] : 0;
    s[threadIdx.x] = v;
    __syncthreads();
    for (int st = 1; st < 256; st <<= 1) {
        int u = (threadIdx.x >= st) ? s[threadIdx.x - st] : 0;
        __syncthreads();
        s[threadIdx.x] += u;
        __syncthreads();
    }
    if (i < N_NODES) {
        int o = bexc[blockIdx.x] + s[threadIdx.x] - v;  // exclusive
        off[i] = o;
        cursor[i] = o;
    }
}

// ---- dis[i] = (1 + deg_i)^-1/2  (self-loop included) ----
__global__ void k_dis(const int* __restrict__ cnt, float* __restrict__ dis) {
    int i = blockIdx.x * blockDim.x + threadIdx.x;
    if (i < N_NODES) dis[i] = rsqrtf(1.0f + (float)cnt[i]);
}

// ---- scatter edges into CSR buckets ----
__global__ void k_fill(const int* __restrict__ row, const int* __restrict__ col,
                       int* __restrict__ cursor, int* __restrict__ csr) {
    int e = blockIdx.x * blockDim.x + threadIdx.x;
    if (e < N_EDGES) {
        int pos = atomicAdd(&cursor[col[e]], 1);
        csr[pos] = row[e];
    }
}

// ---- gather-aggregate: one wave per node, float2 of the 128-dim row per lane ----
__global__ void __launch_bounds__(256) k_gather(const float* __restrict__ x,
                                                const float* __restrict__ dis,
                                                const int* __restrict__ csr,
                                                const int* __restrict__ off,
                                                float* __restrict__ agg) {
    int wave = threadIdx.x >> 6;
    int lane = threadIdx.x & 63;
    int i = blockIdx.x * 4 + wave;
    if (i >= N_NODES) return;
    int start = off[i], end = off[i + 1];
    const float2* x2 = (const float2*)x;
    float2 acc = make_float2(0.f, 0.f);
    for (int base = start; base < end; base += 64) {
        int n = min(64, end - base);
        int s = 0;
        float w = 0.f;
        if (lane < n) {
            s = csr[base + lane];   // coalesced chunk load of sources
            w = dis[s];
        }
        for (int j = 0; j < n; ++j) {
            int sj = __shfl(s, j, 64);
            float wj = __shfl(w, j, 64);
            float2 xv = x2[(size_t)sj * 64 + lane];   // 512B coalesced row read
            acc.x += wj * xv.x;
            acc.y += wj * xv.y;
        }
    }
    float di = dis[i];
    float2 xi = x2[(size_t)i * 64 + lane];
    acc.x = (acc.x + di * xi.x) * di;   // agg = dis_i * (sum_j dis_j x_j + dis_i x_i)
    acc.y = (acc.y + di * xi.y) * di;
    ((float2*)agg)[(size_t)i * 64 + lane] = acc;
}

// ---- linear + LayerNorm, one 128-thread block per node, in-place on agg/out ----
__global__ void __launch_bounds__(128) linear_ln_kernel(
        const float* __restrict__ W,
        const float* __restrict__ bias,
        const float* __restrict__ gamma,
        const float* __restrict__ beta,
        float* __restrict__ out) {
    int i = blockIdx.x;
    int d = threadIdx.x;  // 0..127

    __shared__ float a[DIM];
    __shared__ float red[4];

    size_t base = (size_t)i * DIM;
    a[d] = out[base + d];
    __syncthreads();

    float acc = bias[d];
    const float* w = W + (size_t)d * DIM;
#pragma unroll
    for (int k = 0; k < DIM; k += 4) {
        float4 av = *(const float4*)(a + k);
        float4 wv = *(const float4*)(w + k);
        acc += av.x * wv.x + av.y * wv.y + av.z * wv.z + av.w * wv.w;
    }

    float s = acc, s2 = acc * acc;
#pragma unroll
    for (int offd = 32; offd > 0; offd >>= 1) {
        s  += __shfl_down(s,  offd, 64);
        s2 += __shfl_down(s2, offd, 64);
    }
    int lane = d & 63, wid = d >> 6;
    if (lane == 0) { red[wid] = s; red[2 + wid] = s2; }
    __syncthreads();
    float S  = red[0] + red[1];
    float S2 = red[2] + red[3];
    float mean = S * (1.0f / DIM);
    float var  = S2 * (1.0f / DIM) - mean * mean;
    float inv  = rsqrtf(var + LN_EPS);

    out[base + d] = (acc - mean) * inv * gamma[d] + beta[d];
}

extern "C" void kernel_launch(void* const* d_in, const int* in_sizes, int n_in,
                              void* d_out, int out_size, void* d_ws, size_t ws_size,
                              hipStream_t stream) {
    const float* x     = (const float*)d_in[0];
    const int*   row   = (const int*)d_in[1];                // edge_index[0] (sources)
    const int*   col   = ((const int*)d_in[1]) + N_EDGES;    // edge_index[1] (targets)
    const float* W     = (const float*)d_in[2];
    const float* bias  = (const float*)d_in[3];
    const float* gamma = (const float*)d_in[4];
    const float* beta  = (const float*)d_in[5];
    float* out = (float*)d_out;

    int*   wsi    = (int*)d_ws;
    int*   cnt    = wsi + WS_CNT;
    int*   off    = wsi + WS_OFF;
    int*   cursor = wsi + WS_CURSOR;
    float* dis    = (float*)(wsi + WS_DIS);
    int*   csr    = wsi + WS_CSR;
    int*   bsum   = wsi + WS_BSUM;
    int*   bexc   = wsi + WS_BEXC;

    hipMemsetAsync(cnt, 0, N_NODES * sizeof(int), stream);

    k_count<<<(N_EDGES + 255) / 256, 256, 0, stream>>>(col, cnt);
    k_blockreduce<<<NBLK, 256, 0, stream>>>(cnt, bsum);
    k_scanbsums<<<1, 512, 0, stream>>>(bsum, bexc, off);
    k_blockscan<<<NBLK, 256, 0, stream>>>(cnt, bexc, off, cursor);
    k_dis<<<NBLK, 256, 0, stream>>>(cnt, dis);
    k_fill<<<(N_EDGES + 255) / 256, 256, 0, stream>>>(row, col, cursor, csr);

    k_gather<<<(N_NODES + 3) / 4, 256, 0, stream>>>(x, dis, csr, off, out);

    linear_ln_kernel<<<N_NODES, 128, 0, stream>>>(W, bias, gamma, beta, out);
}

// Round 4
// 786.181 us; speedup vs baseline: 8.0777x; 1.8675x over previous
//
#include <hip/hip_runtime.h>

#define N_NODES 100000
#define N_EDGES 3200000
#define DIM 128
#define LN_EPS 1e-5f
#define NBLK 391            // ceil(N_NODES / 256)

// ---- workspace layout (4-byte elements) ----
#define WS_CNT    0
#define WS_OFF    100000
#define WS_CURSOR 200004
#define WS_DIS    300004
#define WS_CSR    400004
#define WS_BSUM   3600004
#define WS_BEXC   3600516
#define WS_WB     3601028   // 16384 bf16 (8192 ints)

typedef __attribute__((ext_vector_type(8))) short short8;   // bf16x8 MFMA frag
typedef __attribute__((ext_vector_type(4))) float floatx4;  // MFMA acc

__device__ __forceinline__ short f2bf(float f) {
    unsigned u = __float_as_uint(f);
    unsigned r = (u + 0x7FFFu + ((u >> 16) & 1u)) >> 16;   // RNE
    return (short)r;
}

// ---- degree count ----
__global__ void k_count(const int* __restrict__ col, int* __restrict__ cnt) {
    int e = blockIdx.x * blockDim.x + threadIdx.x;
    if (e < N_EDGES) atomicAdd(&cnt[col[e]], 1);
}

__global__ void k_blockreduce(const int* __restrict__ cnt, int* __restrict__ bsum) {
    __shared__ int s[256];
    int i = blockIdx.x * 256 + threadIdx.x;
    s[threadIdx.x] = (i < N_NODES) ? cnt[i] : 0;
    __syncthreads();
    for (int st = 128; st > 0; st >>= 1) {
        if (threadIdx.x < st) s[threadIdx.x] += s[threadIdx.x + st];
        __syncthreads();
    }
    if (threadIdx.x == 0) bsum[blockIdx.x] = s[0];
}

__global__ void k_scanbsums(const int* __restrict__ bsum, int* __restrict__ bexc,
                            int* __restrict__ off) {
    __shared__ int s[512];
    int t = threadIdx.x;
    int v0 = (t < NBLK) ? bsum[t] : 0;
    s[t] = v0;
    __syncthreads();
    for (int st = 1; st < 512; st <<= 1) {
        int v = (t >= st) ? s[t - st] : 0;
        __syncthreads();
        s[t] += v;
        __syncthreads();
    }
    if (t < NBLK) bexc[t] = s[t] - v0;
    if (t == 0) off[N_NODES] = N_EDGES;
}

__global__ void k_blockscan(const int* __restrict__ cnt, const int* __restrict__ bexc,
                            int* __restrict__ off, int* __restrict__ cursor) {
    __shared__ int s[256];
    int i = blockIdx.x * 256 + threadIdx.x;
    int v = (i < N_NODES) ? cnt[i] : 0;
    s[threadIdx.x] = v;
    __syncthreads();
    for (int st = 1; st < 256; st <<= 1) {
        int u = (threadIdx.x >= st) ? s[threadIdx.x - st] : 0;
        __syncthreads();
        s[threadIdx.x] += u;
        __syncthreads();
    }
    if (i < N_NODES) {
        int o = bexc[blockIdx.x] + s[threadIdx.x] - v;
        off[i] = o;
        cursor[i] = o;
    }
}

__global__ void k_dis(const int* __restrict__ cnt, float* __restrict__ dis) {
    int i = blockIdx.x * blockDim.x + threadIdx.x;
    if (i < N_NODES) dis[i] = rsqrtf(1.0f + (float)cnt[i]);
}

__global__ void k_fill(const int* __restrict__ row, const int* __restrict__ col,
                       int* __restrict__ cursor, int* __restrict__ csr) {
    int e = blockIdx.x * blockDim.x + threadIdx.x;
    if (e < N_EDGES) {
        int pos = atomicAdd(&cursor[col[e]], 1);
        csr[pos] = row[e];
    }
}

// ---- W fp32 -> bf16 ----
__global__ void k_wconv(const float* __restrict__ W, short* __restrict__ Wb) {
    int i = blockIdx.x * 256 + threadIdx.x;
    if (i < DIM * DIM) Wb[i] = f2bf(W[i]);
}

// ---- gather-aggregate (R2 version, verified passing): one wave per node, float2/lane ----
__global__ void __launch_bounds__(256) k_gather(const float* __restrict__ x,
                                                const float* __restrict__ dis,
                                                const int* __restrict__ csr,
                                                const int* __restrict__ off,
                                                float* __restrict__ agg) {
    int wave = threadIdx.x >> 6;
    int lane = threadIdx.x & 63;
    int i = blockIdx.x * 4 + wave;
    if (i >= N_NODES) return;
    int start = off[i], end = off[i + 1];
    const float2* x2 = (const float2*)x;
    float2 acc = make_float2(0.f, 0.f);
    for (int base = start; base < end; base += 64) {
        int n = min(64, end - base);
        int s = 0;
        float w = 0.f;
        if (lane < n) {
            s = csr[base + lane];   // coalesced chunk load of sources
            w = dis[s];
        }
        for (int j = 0; j < n; ++j) {
            int sj = __shfl(s, j, 64);
            float wj = __shfl(w, j, 64);
            float2 xv = x2[(size_t)sj * 64 + lane];   // 512B coalesced row read
            acc.x += wj * xv.x;
            acc.y += wj * xv.y;
        }
    }
    float di = dis[i];
    float2 xi = x2[(size_t)i * 64 + lane];
    acc.x = (acc.x + di * xi.x) * di;   // agg = dis_i * (sum_j dis_j x_j + dis_i x_i)
    acc.y = (acc.y + di * xi.y) * di;
    ((float2*)agg)[(size_t)i * 64 + lane] = acc;
}

// ---- linear + LayerNorm via bf16 MFMA: one wave per 16 nodes, in-place on agg/out ----
// mfma_f32_16x16x32_bf16: A[m=lane&15][k=(lane>>4)*8+j]; B[k=(lane>>4)*8+j][n=lane&15];
// C/D: col=lane&15, row=(lane>>4)*4+reg  [verified layouts, learn_hip m89/m91/m120]
// NOTE: agg/out intentionally NOT __restrict__ (same buffer, in-place).
__global__ void __launch_bounds__(256) k_linear_ln_mfma(
        const float* agg,                 // == out, fp32, read-then-overwrite per node row
        const short* __restrict__ Wb,     // bf16 W [DIM][DIM] row-major
        const float* __restrict__ bias,
        const float* __restrict__ gamma,
        const float* __restrict__ beta,
        float* out) {
    int wave = threadIdx.x >> 6;
    int lane = threadIdx.x & 63;
    int i0 = (blockIdx.x * 4 + wave) * 16;   // 16 nodes per wave; 100000 % 16 == 0
    if (i0 >= N_NODES) return;
    int m = lane & 15;
    int q = lane >> 4;

    floatx4 acc[8];
#pragma unroll
    for (int t = 0; t < 8; ++t) acc[t] = (floatx4){0.f, 0.f, 0.f, 0.f};

#pragma unroll
    for (int s = 0; s < 4; ++s) {
        int k0 = s * 32 + q * 8;
        const float* ap = agg + (size_t)(i0 + m) * DIM + k0;
        float4 a0 = *(const float4*)ap;
        float4 a1 = *(const float4*)(ap + 4);
        short8 af;
        af[0] = f2bf(a0.x); af[1] = f2bf(a0.y); af[2] = f2bf(a0.z); af[3] = f2bf(a0.w);
        af[4] = f2bf(a1.x); af[5] = f2bf(a1.y); af[6] = f2bf(a1.z); af[7] = f2bf(a1.w);
#pragma unroll
        for (int t = 0; t < 8; ++t) {
            short8 bf = *(const short8*)(Wb + (size_t)(t * 16 + m) * DIM + k0);
            acc[t] = __builtin_amdgcn_mfma_f32_16x16x32_bf16(af, bf, acc[t], 0, 0, 0);
        }
    }

    // epilogue: bias + LayerNorm per node row
    float bv[8], gv[8], btv[8];
#pragma unroll
    for (int t = 0; t < 8; ++t) {
        int dim = t * 16 + m;           // col = lane&15
        bv[t] = bias[dim]; gv[t] = gamma[dim]; btv[t] = beta[dim];
    }
    float S[4], S2[4];
#pragma unroll
    for (int r = 0; r < 4; ++r) {
        float s = 0.f, s2 = 0.f;
#pragma unroll
        for (int t = 0; t < 8; ++t) {
            float v = acc[t][r] + bv[t];
            s += v; s2 += v * v;
        }
        S[r] = s; S2[r] = s2;
    }
    // reduce across the 16 lanes of this q-group (xor masks < 16 stay in-group)
#pragma unroll
    for (int mask = 1; mask < 16; mask <<= 1) {
#pragma unroll
        for (int r = 0; r < 4; ++r) {
            S[r]  += __shfl_xor(S[r],  mask, 64);
            S2[r] += __shfl_xor(S2[r], mask, 64);
        }
    }
#pragma unroll
    for (int r = 0; r < 4; ++r) {
        float mean = S[r] * (1.0f / DIM);
        float var  = S2[r] * (1.0f / DIM) - mean * mean;
        float inv  = rsqrtf(var + LN_EPS);
        int node = i0 + q * 4 + r;      // row = (lane>>4)*4 + reg
#pragma unroll
        for (int t = 0; t < 8; ++t) {
            float v = acc[t][r] + bv[t];
            out[(size_t)node * DIM + t * 16 + m] = (v - mean) * inv * gv[t] + btv[t];
        }
    }
}

extern "C" void kernel_launch(void* const* d_in, const int* in_sizes, int n_in,
                              void* d_out, int out_size, void* d_ws, size_t ws_size,
                              hipStream_t stream) {
    const float* x     = (const float*)d_in[0];
    const int*   row   = (const int*)d_in[1];                // edge_index[0] (sources)
    const int*   col   = ((const int*)d_in[1]) + N_EDGES;    // edge_index[1] (targets)
    const float* W     = (const float*)d_in[2];
    const float* bias  = (const float*)d_in[3];
    const float* gamma = (const float*)d_in[4];
    const float* beta  = (const float*)d_in[5];
    float* out = (float*)d_out;

    int*   wsi    = (int*)d_ws;
    int*   cnt    = wsi + WS_CNT;
    int*   off    = wsi + WS_OFF;
    int*   cursor = wsi + WS_CURSOR;
    float* dis    = (float*)(wsi + WS_DIS);
    int*   csr    = wsi + WS_CSR;
    int*   bsum   = wsi + WS_BSUM;
    int*   bexc   = wsi + WS_BEXC;
    short* Wb     = (short*)(wsi + WS_WB);

    hipMemsetAsync(cnt, 0, N_NODES * sizeof(int), stream);

    k_wconv<<<(DIM * DIM + 255) / 256, 256, 0, stream>>>(W, Wb);
    k_count<<<(N_EDGES + 255) / 256, 256, 0, stream>>>(col, cnt);
    k_blockreduce<<<NBLK, 256, 0, stream>>>(cnt, bsum);
    k_scanbsums<<<1, 512, 0, stream>>>(bsum, bexc, off);
    k_blockscan<<<NBLK, 256, 0, stream>>>(cnt, bexc, off, cursor);
    k_dis<<<NBLK, 256, 0, stream>>>(cnt, dis);
    k_fill<<<(N_EDGES + 255) / 256, 256, 0, stream>>>(row, col, cursor, csr);

    k_gather<<<(N_NODES + 3) / 4, 256, 0, stream>>>(x, dis, csr, off, out);

    k_linear_ln_mfma<<<(N_NODES / 16 + 3) / 4, 256, 0, stream>>>(
        out, Wb, bias, gamma, beta, out);
}